// Round 6
// baseline (1114.044 us; speedup 1.0000x reference)
//
#include <hip/hip_runtime.h>
#include <math.h>

// Llama4TextMoe — bf16 MFMA, round 6: merged up-kernel + double-buffered LDS with
// one raw barrier per K-step.
// r5-validated pieces kept identical: tr_b16 B layout (128B-aligned 4x16 tiles,
// b_slot staging map, TR8 offsets), A fragment map, epilogues, bookkeeping.
// New: {frag-read buf[cur] | stage buf[nxt] | gload kt+2} -> lgkm fence -> MFMA
//      -> raw s_barrier (no vmcnt drain; 2-deep global prefetch stays in flight).

#define BM 128
#define BN 64
#define BK 32
#define LDPA 40      // A row pitch (bf16 elems)
#define MAXT 64
#define BMAT 4096    // bytes per B matrix in LDS (4 nblk * 8 kblk * 128B)

typedef float f32x4 __attribute__((ext_vector_type(4)));
typedef short bf16x8 __attribute__((ext_vector_type(8)));
typedef short bf16x4 __attribute__((ext_vector_type(4)));
typedef __bf16 bf2 __attribute__((ext_vector_type(2)));

union B8 { bf16x8 v; struct { bf16x4 lo, hi; } h; };

__device__ inline unsigned int pk2(float a, float b) {
    union { bf2 h; unsigned int u; } c;
    c.h[0] = (__bf16)a; c.h[1] = (__bf16)b;   // v_cvt_pk_bf16_f32
    return c.u;
}
__device__ inline unsigned long long pk4(float4 v) {
    return (unsigned long long)pk2(v.x, v.y) | ((unsigned long long)pk2(v.z, v.w) << 32);
}
__device__ inline unsigned short f2bf(float a) {
    union { __bf16 h; unsigned short u; } c; c.h = (__bf16)a; return c.u;
}
__device__ inline bf16x8 pk8(float4 a, float4 b) {
    union { bf16x8 v; unsigned int u[4]; } c;
    c.u[0] = pk2(a.x, a.y); c.u[1] = pk2(a.z, a.w);
    c.u[2] = pk2(b.x, b.y); c.u[3] = pk2(b.z, b.w);
    return c.v;
}

// two transpose-reads -> one bf16x8 frag: elem j = B[8*(lane>>4)+j][nblk*16+(lane&15)]
#define TR8(U, ADDR, IMM0, IMM1) \
    asm volatile("ds_read_b64_tr_b16 %0, %2 offset:" IMM0 "\n\t" \
                 "ds_read_b64_tr_b16 %1, %2 offset:" IMM1 \
                 : "=&v"((U).h.lo), "=&v"((U).h.hi) : "v"(ADDR))

#define LGKM_FENCE() do { \
    asm volatile("s_waitcnt lgkmcnt(0)" ::: "memory"); \
    __builtin_amdgcn_sched_barrier(0); } while (0)

// B staging slot for flat index s (0..511): thread writes 4 n-consecutive elems of row k.
__device__ inline void b_slot(int s, int* k, int* nq, int* off) {
    *k  = s >> 4;            // 0..31
    *nq = s & 15;            // n quad 0..15 (64 cols)
    *off = ((*nq) >> 2) * 1024 + ((*k) >> 2) * 128 + ((*k) & 3) * 32 + ((*nq) & 3) * 8;
}

// ---------------- router / bookkeeping ----------------

__global__ __launch_bounds__(256) void router_kernel(
    const float* __restrict__ x, const float* __restrict__ rw,
    float* __restrict__ scores_out, int* __restrict__ eidx,
    float* __restrict__ score, int* __restrict__ counts, int T, int H, int E)
{
    int g = blockIdx.x * 256 + threadIdx.x;
    int t = g >> 3, e = g & 7;          // E == 8
    if (t >= T) return;
    const float4* xr4 = (const float4*)(x + (size_t)t * H);
    float acc = 0.f;
    for (int k4 = 0; k4 < H / 4; k4++) {
        float4 xv = xr4[k4];
        int k = 4 * k4;
        acc = fmaf(xv.x, rw[(k + 0) * E + e], acc);
        acc = fmaf(xv.y, rw[(k + 1) * E + e], acc);
        acc = fmaf(xv.z, rw[(k + 2) * E + e], acc);
        acc = fmaf(xv.w, rw[(k + 3) * E + e], acc);
    }
    float bv = acc; int bi = e;
    #pragma unroll
    for (int off = 4; off; off >>= 1) {
        float ov = __shfl_xor(bv, off, 8);
        int   oi = __shfl_xor(bi, off, 8);
        if (ov > bv || (ov == bv && oi < bi)) { bv = ov; bi = oi; }
    }
    float sig = 1.f / (1.f + __expf(-bv));
    scores_out[(size_t)e * T + t] = (e == bi) ? sig : 0.f;
    if (e == 0) {
        eidx[t] = bi;
        score[t] = sig;
        atomicAdd(&counts[bi], 1);
    }
}

__global__ void prefix_kernel(const int* __restrict__ counts, int* __restrict__ offs,
                              int* __restrict__ tile_e, int* __restrict__ tile_m,
                              int* __restrict__ ntile, int E)
{
    if (blockIdx.x == 0 && threadIdx.x == 0) {
        int run = 0, nt = 0;
        for (int e = 0; e < E; e++) {
            offs[e] = run;
            int c = counts[e];
            int t = (c + BM - 1) / BM;
            for (int i = 0; i < t; i++) { tile_e[nt] = e; tile_m[nt] = i * BM; nt++; }
            run += t * BM;
        }
        ntile[0] = nt;
    }
}

__global__ __launch_bounds__(256) void scatter_kernel(
    const int* __restrict__ eidx, const int* __restrict__ offs,
    int* __restrict__ cursor, int* __restrict__ list, int T)
{
    int t = blockIdx.x * 256 + threadIdx.x;
    if (t >= T) return;
    int e = eidx[t];
    int pos = offs[e] + atomicAdd(&cursor[e], 1);
    list[pos] = t;
}

// ---------------- merged up (shared tiles + routed tiles, fused SwiGLU) ----------------

__global__ __launch_bounds__(256, 3) void up_gemm(
    const float* __restrict__ X, const float* __restrict__ Wg,
    const float* __restrict__ Wu, const float* __restrict__ GUP,
    const int* __restrict__ counts, const int* __restrict__ offs,
    const int* __restrict__ list, const float* __restrict__ score,
    const int* __restrict__ tile_e, const int* __restrict__ tile_m,
    const int* __restrict__ ntile,
    unsigned short* __restrict__ sharedH, unsigned short* __restrict__ routedH,
    int H, int I, int T)
{
    const int TS = T / BM;               // shared tiles first
    const int gt = blockIdx.y;
    const bool isShared = gt < TS;
    int e = 0, mbase, count = 0, off_e = 0;
    if (isShared) {
        mbase = gt * BM;
    } else {
        int idx = gt - TS;
        if (idx >= ntile[0]) return;
        e = tile_e[idx]; mbase = tile_m[idx];
        count = counts[e]; off_e = offs[e];
    }

    __shared__ __attribute__((aligned(16)))  short A0s[BM][LDPA], A1s[BM][LDPA];
    __shared__ __attribute__((aligned(128))) char B0s[2 * BMAT], B1s[2 * BMAT];

    const int tid = threadIdx.x;
    const int lane = tid & 63, wid = tid >> 6;
    const int wr = wid >> 1, wc = wid & 1;
    const int n0 = blockIdx.x * BN;

    // A: thread -> row tid>>1, 16-k half (tid&1); 64B contiguous load
    const int am = tid >> 1, ak = (tid & 1) * 16;
    int tok; float sA;
    if (isShared) { tok = mbase + am; sA = 1.f; }
    else {
        int gr = mbase + am; tok = 0; sA = 0.f;
        if (gr < count) { tok = list[off_e + gr]; sA = score[tok]; }
    }
    const float* apA = X + (size_t)tok * H + ak;

    const float* baseg; const float* baseu; size_t ldb;
    if (isShared) { baseg = Wg; baseu = Wu; ldb = (size_t)I; }
    else { baseg = GUP + (size_t)e * H * (2 * I); baseu = baseg + I; ldb = 2 * (size_t)I; }

    int boff[2];
    const float *gsrc[2], *usrc[2];
#pragma unroll
    for (int p = 0; p < 2; p++) {
        int k, nq, off;
        b_slot(tid + p * 256, &k, &nq, &off);
        boff[p] = off;
        gsrc[p] = baseg + (size_t)k * ldb + (n0 + 4 * nq);
        usrc[p] = baseu + (size_t)k * ldb + (n0 + 4 * nq);
    }
    const int btr0 = (int)(size_t)B0s + wc * 2048 + (lane >> 4) * 256 + 8 * (lane & 15);
    const int btr1 = (int)(size_t)B1s + wc * 2048 + (lane >> 4) * 256 + 8 * (lane & 15);

    f32x4 accg[4][2], accu[4][2];
#pragma unroll
    for (int i = 0; i < 4; i++)
#pragma unroll
        for (int j = 0; j < 2; j++) {
            accg[i][j] = (f32x4){0.f, 0.f, 0.f, 0.f};
            accu[i][j] = (f32x4){0.f, 0.f, 0.f, 0.f};
        }

    float4 va[4], vg[2], vu[2];
    auto GLOAD = [&](int k0) {
#pragma unroll
        for (int q = 0; q < 4; q++) va[q] = *(const float4*)(apA + k0 + q * 4);
#pragma unroll
        for (int p = 0; p < 2; p++) {
            vg[p] = *(const float4*)(gsrc[p] + (size_t)k0 * ldb);
            vu[p] = *(const float4*)(usrc[p] + (size_t)k0 * ldb);
        }
    };
    auto STAGE = [&](short* Ab, char* Bb) {
        short* ad = Ab + am * LDPA + ak;
        float4 s0 = make_float4(va[0].x * sA, va[0].y * sA, va[0].z * sA, va[0].w * sA);
        float4 s1 = make_float4(va[1].x * sA, va[1].y * sA, va[1].z * sA, va[1].w * sA);
        float4 s2 = make_float4(va[2].x * sA, va[2].y * sA, va[2].z * sA, va[2].w * sA);
        float4 s3 = make_float4(va[3].x * sA, va[3].y * sA, va[3].z * sA, va[3].w * sA);
        *(bf16x8*)ad       = pk8(s0, s1);
        *(bf16x8*)(ad + 8) = pk8(s2, s3);
#pragma unroll
        for (int p = 0; p < 2; p++) {
            *(unsigned long long*)(Bb + boff[p])        = pk4(vg[p]);
            *(unsigned long long*)(Bb + boff[p] + BMAT) = pk4(vu[p]);
        }
    };
    const int kh = (lane >> 4) * 8;
    bf16x8 af[4]; B8 gf[2], uf[2];
    auto AFRAGS = [&](short* Ab) {
#pragma unroll
        for (int q = 0; q < 4; q++)
            af[q] = *(const bf16x8*)(Ab + (wr * 64 + q * 16 + (lane & 15)) * LDPA + kh);
    };
    auto MF = [&]() {
#pragma unroll
        for (int mi = 0; mi < 4; mi++)
#pragma unroll
            for (int nj = 0; nj < 2; nj++) {
                accg[mi][nj] = __builtin_amdgcn_mfma_f32_16x16x32_bf16(af[mi], gf[nj].v, accg[mi][nj], 0, 0, 0);
                accu[mi][nj] = __builtin_amdgcn_mfma_f32_16x16x32_bf16(af[mi], uf[nj].v, accu[mi][nj], 0, 0, 0);
            }
    };

    const int nK = H / BK;               // 64, even
    GLOAD(0);
    STAGE(&A0s[0][0], B0s);
    GLOAD(BK);
    LGKM_FENCE();
    __builtin_amdgcn_s_barrier();

    for (int kt = 0; kt < nK; kt += 2) {
        // phase even: compute buf0 (tile kt), stage buf1 (tile kt+1), load kt+2
        AFRAGS(&A0s[0][0]);
        TR8(gf[0], btr0, "0",    "128");
        TR8(gf[1], btr0, "1024", "1152");
        TR8(uf[0], btr0, "4096", "4224");
        TR8(uf[1], btr0, "5120", "5248");
        STAGE(&A1s[0][0], B1s);
        if (kt + 2 < nK) GLOAD((kt + 2) * BK);
        LGKM_FENCE();
        MF();
        __builtin_amdgcn_s_barrier();
        // phase odd: compute buf1 (tile kt+1), stage buf0 (tile kt+2), load kt+3
        AFRAGS(&A1s[0][0]);
        TR8(gf[0], btr1, "0",    "128");
        TR8(gf[1], btr1, "1024", "1152");
        TR8(uf[0], btr1, "4096", "4224");
        TR8(uf[1], btr1, "5120", "5248");
        if (kt + 2 < nK) STAGE(&A0s[0][0], B0s);
        if (kt + 3 < nK) GLOAD((kt + 3) * BK);
        LGKM_FENCE();
        MF();
        __builtin_amdgcn_s_barrier();
    }

    unsigned short* outp = isShared ? sharedH : routedH;
    const int rowbase = isShared ? mbase : off_e + mbase;
    const int rb = (lane >> 4) * 4, cb = lane & 15;
#pragma unroll
    for (int mi = 0; mi < 4; mi++)
#pragma unroll
        for (int nj = 0; nj < 2; nj++) {
            int col = n0 + wc * 32 + nj * 16 + cb;
#pragma unroll
            for (int j = 0; j < 4; j++) {
                float g = accg[mi][nj][j], u = accu[mi][nj][j];
                float r = u * g * __builtin_amdgcn_rcpf(1.f + __expf(-g));
                int row = rowbase + wr * 64 + mi * 16 + rb + j;
                outp[(size_t)row * I + col] = f2bf(r);
            }
        }
}

// ---------------- fused down: out[tok] = SH[tok]@Wsd + RH[slot]@Dp_e ----------------

__global__ __launch_bounds__(256, 2) void fused_down(
    const unsigned short* __restrict__ SH, const unsigned short* __restrict__ RH,
    const float* __restrict__ Wsd, const float* __restrict__ DP,
    const int* __restrict__ counts, const int* __restrict__ offs,
    const int* __restrict__ list,
    const int* __restrict__ tile_e, const int* __restrict__ tile_m,
    const int* __restrict__ ntile,
    float* __restrict__ out, int I, int H)
{
    const int gt = blockIdx.y;
    if (gt >= ntile[0]) return;
    const int e = tile_e[gt], mbase = tile_m[gt];
    const int count = counts[e], off_e = offs[e];
    const float* W2 = DP + (size_t)e * I * H;

    __shared__ __attribute__((aligned(16)))  short SA0[BM][LDPA], SA1[BM][LDPA];
    __shared__ __attribute__((aligned(16)))  short RA0[BM][LDPA], RA1[BM][LDPA];
    __shared__ __attribute__((aligned(128))) char B0s[2 * BMAT], B1s[2 * BMAT];
    __shared__ int toks[BM];

    const int tid = threadIdx.x;
    const int lane = tid & 63, wid = tid >> 6;
    const int wr = wid >> 1, wc = wid & 1;
    const int n0 = blockIdx.x * BN;

    if (tid < BM) {
        int gr = mbase + tid;
        toks[tid] = (gr < count) ? list[off_e + gr] : -1;
    }
    __syncthreads();

    const int am = tid >> 1, ak = (tid & 1) * 16;
    int tokA = toks[am]; if (tokA < 0) tokA = 0;
    const unsigned short* a1p = SH + (size_t)tokA * I + ak;
    const unsigned short* a2p = RH + (size_t)(off_e + mbase + am) * I + ak;

    int boff[2];
    const float *b1s[2], *b2s[2];
#pragma unroll
    for (int p = 0; p < 2; p++) {
        int k, nq, off;
        b_slot(tid + p * 256, &k, &nq, &off);
        boff[p] = off;
        b1s[p] = Wsd + (size_t)k * H + (n0 + 4 * nq);
        b2s[p] = W2  + (size_t)k * H + (n0 + 4 * nq);
    }
    const int btr0 = (int)(size_t)B0s + wc * 2048 + (lane >> 4) * 256 + 8 * (lane & 15);
    const int btr1 = (int)(size_t)B1s + wc * 2048 + (lane >> 4) * 256 + 8 * (lane & 15);

    f32x4 acc[4][2];
#pragma unroll
    for (int i = 0; i < 4; i++)
#pragma unroll
        for (int j = 0; j < 2; j++) acc[i][j] = (f32x4){0.f, 0.f, 0.f, 0.f};

    bf16x8 w1[2], w2[2];
    float4 vb1[2], vb2[2];
    auto GLOAD = [&](int k0) {
        w1[0] = *(const bf16x8*)(a1p + k0); w1[1] = *(const bf16x8*)(a1p + k0 + 8);
        w2[0] = *(const bf16x8*)(a2p + k0); w2[1] = *(const bf16x8*)(a2p + k0 + 8);
#pragma unroll
        for (int p = 0; p < 2; p++) {
            vb1[p] = *(const float4*)(b1s[p] + (size_t)k0 * H);
            vb2[p] = *(const float4*)(b2s[p] + (size_t)k0 * H);
        }
    };
    auto STAGE = [&](short* S, short* R, char* Bb) {
        short* sd = S + am * LDPA + ak;
        short* rd = R + am * LDPA + ak;
        *(bf16x8*)sd       = w1[0];
        *(bf16x8*)(sd + 8) = w1[1];
        *(bf16x8*)rd       = w2[0];
        *(bf16x8*)(rd + 8) = w2[1];
#pragma unroll
        for (int p = 0; p < 2; p++) {
            *(unsigned long long*)(Bb + boff[p])        = pk4(vb1[p]);
            *(unsigned long long*)(Bb + boff[p] + BMAT) = pk4(vb2[p]);
        }
    };
    const int kh = (lane >> 4) * 8;
    bf16x8 af1[4], af2[4]; B8 b1f[2], b2f[2];
    auto AFRAGS = [&](short* S, short* R) {
#pragma unroll
        for (int q = 0; q < 4; q++) {
            int ro = (wr * 64 + q * 16 + (lane & 15)) * LDPA + kh;
            af1[q] = *(const bf16x8*)(S + ro);
            af2[q] = *(const bf16x8*)(R + ro);
        }
    };
    auto MF = [&]() {
#pragma unroll
        for (int mi = 0; mi < 4; mi++)
#pragma unroll
            for (int nj = 0; nj < 2; nj++) {
                acc[mi][nj] = __builtin_amdgcn_mfma_f32_16x16x32_bf16(af1[mi], b1f[nj].v, acc[mi][nj], 0, 0, 0);
                acc[mi][nj] = __builtin_amdgcn_mfma_f32_16x16x32_bf16(af2[mi], b2f[nj].v, acc[mi][nj], 0, 0, 0);
            }
    };

    const int nK = I / BK;               // 128, even
    GLOAD(0);
    STAGE(&SA0[0][0], &RA0[0][0], B0s);
    GLOAD(BK);
    LGKM_FENCE();
    __builtin_amdgcn_s_barrier();

    for (int kt = 0; kt < nK; kt += 2) {
        AFRAGS(&SA0[0][0], &RA0[0][0]);
        TR8(b1f[0], btr0, "0",    "128");
        TR8(b1f[1], btr0, "1024", "1152");
        TR8(b2f[0], btr0, "4096", "4224");
        TR8(b2f[1], btr0, "5120", "5248");
        STAGE(&SA1[0][0], &RA1[0][0], B1s);
        if (kt + 2 < nK) GLOAD((kt + 2) * BK);
        LGKM_FENCE();
        MF();
        __builtin_amdgcn_s_barrier();

        AFRAGS(&SA1[0][0], &RA1[0][0]);
        TR8(b1f[0], btr1, "0",    "128");
        TR8(b1f[1], btr1, "1024", "1152");
        TR8(b2f[0], btr1, "4096", "4224");
        TR8(b2f[1], btr1, "5120", "5248");
        if (kt + 2 < nK) STAGE(&SA0[0][0], &RA0[0][0], B0s);
        if (kt + 3 < nK) GLOAD((kt + 3) * BK);
        LGKM_FENCE();
        MF();
        __builtin_amdgcn_s_barrier();
    }

    const int rb = (lane >> 4) * 4, cb = lane & 15;
#pragma unroll
    for (int mi = 0; mi < 4; mi++)
#pragma unroll
        for (int nj = 0; nj < 2; nj++) {
            int col = n0 + wc * 32 + nj * 16 + cb;
#pragma unroll
            for (int j = 0; j < 4; j++) {
                int lr = wr * 64 + mi * 16 + rb + j;
                int tok = toks[lr];
                if (tok >= 0) out[(size_t)tok * H + col] = acc[mi][nj][j];
            }
        }
}

// ---------------- launcher ----------------

extern "C" void kernel_launch(void* const* d_in, const int* in_sizes, int n_in,
                              void* d_out, int out_size, void* d_ws, size_t ws_size,
                              hipStream_t stream)
{
    const float* x   = (const float*)d_in[0];
    const float* rw  = (const float*)d_in[1];
    const float* gup = (const float*)d_in[2];
    const float* dp  = (const float*)d_in[3];
    const float* sg  = (const float*)d_in[4];
    const float* su  = (const float*)d_in[5];
    const float* sd  = (const float*)d_in[6];

    const int H = 2048, I = 4096, E = 8;
    const int T = in_sizes[0] / H;            // 2048

    float* out        = (float*)d_out;
    float* scores_out = out + (size_t)T * H;  // router_scores [E, T]

    const int slotsCap = T + E * BM;          // 3072
    unsigned short* routedH = (unsigned short*)d_ws;                  // [slotsCap, I] bf16
    unsigned short* sharedH = routedH + (size_t)slotsCap * I;         // [T, I] bf16
    int*   list   = (int*)(sharedH + (size_t)T * I);                  // [slotsCap]
    int*   eidx   = list + slotsCap;                                  // [T]
    float* score  = (float*)(eidx + T);                               // [T]
    int*   counts = (int*)(score + T);                                // [E]
    int*   cursor = counts + E;                                       // [E]
    int*   offs   = cursor + E;                                       // [E]
    int*   ntile  = offs + E;                                         // [1]
    int*   tile_e = ntile + 1;                                        // [MAXT]
    int*   tile_m = tile_e + MAXT;                                    // [MAXT]

    const int maxRTiles = T / BM + E;         // 24 routed tiles worst case
    const int maxUTiles = T / BM + maxRTiles; // 16 shared + routed

    hipMemsetAsync(counts, 0, 2 * E * sizeof(int), stream);
    router_kernel<<<(T * E) / 256, 256, 0, stream>>>(x, rw, scores_out, eidx, score, counts, T, H, E);
    prefix_kernel<<<1, 1, 0, stream>>>(counts, offs, tile_e, tile_m, ntile, E);
    scatter_kernel<<<(T + 255) / 256, 256, 0, stream>>>(eidx, offs, cursor, list, T);
    up_gemm<<<dim3(I / BN, maxUTiles), 256, 0, stream>>>(x, sg, su, gup, counts, offs, list, score,
                                                         tile_e, tile_m, ntile, sharedH, routedH, H, I, T);
    fused_down<<<dim3(H / BN, maxRTiles), 256, 0, stream>>>(sharedH, routedH, sd, dp,
                                                            counts, offs, list,
                                                            tile_e, tile_m, ntile, out, I, H);
}

// Round 7
// 877.753 us; speedup vs baseline: 1.2692x; 1.2692x over previous
//
#include <hip/hip_runtime.h>
#include <math.h>

// Llama4TextMoe — round 7: m97-structure GEMMs (global_load_lds + linear LDS +
// ds_read_b128 frags, 2-barrier loop) fed by a bf16 prep pass.
//   prep: transpose-convert all weights fp32[K][N] -> bf16[N][K]; X -> bf16;
//         XS (slot-ordered, score-scaled, gathered, pads zeroed) -> bf16.
//   up_gemm: merged shared+routed tiles; A=Xbf/XSbf rows, B=W^T rows; all staging
//            via global_load_lds width16 (no staging VALU/LDS-write instrs).
//   fused_down: out[tok] = SH[tok]@WsdT^T + RH[slot]@dpT_e^T, same structure.
// Frag maps identical to the r2/r5-validated ones (A rows / B n-rows, b128 at
// row*64B + (lane>>4)*16B — bank-even). XCD-chunk swizzle groups same-B blocks.

#define BM 128
#define BN 64
#define BK 32
#define MAXT 32

typedef float f32x4 __attribute__((ext_vector_type(4)));
typedef short bf16x8 __attribute__((ext_vector_type(8)));
typedef __bf16 bf2 __attribute__((ext_vector_type(2)));

__device__ inline unsigned int pk2(float a, float b) {
    union { bf2 h; unsigned int u; } c;
    c.h[0] = (__bf16)a; c.h[1] = (__bf16)b;   // v_cvt_pk_bf16_f32
    return c.u;
}
__device__ inline unsigned short f2bf(float a) {
    union { __bf16 h; unsigned short u; } c; c.h = (__bf16)a; return c.u;
}
__device__ inline bf16x8 pk8(float4 a, float4 b) {
    union { bf16x8 v; unsigned int u[4]; } c;
    c.u[0] = pk2(a.x, a.y); c.u[1] = pk2(a.z, a.w);
    c.u[2] = pk2(b.x, b.y); c.u[3] = pk2(b.z, b.w);
    return c.v;
}

// global -> LDS DMA, 16B per lane; dest = (wave-uniform lds) + lane*16.
__device__ inline void gload16(const void* g, void* l) {
    __builtin_amdgcn_global_load_lds(
        (const __attribute__((address_space(1))) void*)(unsigned long long)g,
        (__attribute__((address_space(3))) void*)(unsigned int)(unsigned long long)l,
        16, 0, 0);
}

// ---------------- router / bookkeeping (validated) ----------------

__global__ __launch_bounds__(256) void router_kernel(
    const float* __restrict__ x, const float* __restrict__ rw,
    float* __restrict__ scores_out, int* __restrict__ eidx,
    float* __restrict__ score, int* __restrict__ counts, int T, int H, int E)
{
    int g = blockIdx.x * 256 + threadIdx.x;
    int t = g >> 3, e = g & 7;          // E == 8
    if (t >= T) return;
    const float4* xr4 = (const float4*)(x + (size_t)t * H);
    float acc = 0.f;
    for (int k4 = 0; k4 < H / 4; k4++) {
        float4 xv = xr4[k4];
        int k = 4 * k4;
        acc = fmaf(xv.x, rw[(k + 0) * E + e], acc);
        acc = fmaf(xv.y, rw[(k + 1) * E + e], acc);
        acc = fmaf(xv.z, rw[(k + 2) * E + e], acc);
        acc = fmaf(xv.w, rw[(k + 3) * E + e], acc);
    }
    float bv = acc; int bi = e;
    #pragma unroll
    for (int off = 4; off; off >>= 1) {
        float ov = __shfl_xor(bv, off, 8);
        int   oi = __shfl_xor(bi, off, 8);
        if (ov > bv || (ov == bv && oi < bi)) { bv = ov; bi = oi; }
    }
    float sig = 1.f / (1.f + __expf(-bv));
    scores_out[(size_t)e * T + t] = (e == bi) ? sig : 0.f;
    if (e == 0) {
        eidx[t] = bi;
        score[t] = sig;
        atomicAdd(&counts[bi], 1);
    }
}

__global__ void prefix_kernel(const int* __restrict__ counts, int* __restrict__ offs,
                              int* __restrict__ tile_e, int* __restrict__ tile_m,
                              int* __restrict__ ntile, int E)
{
    if (blockIdx.x == 0 && threadIdx.x == 0) {
        int run = 0, nt = 0;
        for (int e = 0; e < E; e++) {
            offs[e] = run;
            int c = counts[e];
            int t = (c + BM - 1) / BM;
            for (int i = 0; i < t; i++) { tile_e[nt] = e; tile_m[nt] = i * BM; nt++; }
            run += t * BM;
        }
        ntile[0] = nt;
    }
}

__global__ __launch_bounds__(256) void scatter_kernel(
    const int* __restrict__ eidx, const int* __restrict__ offs,
    int* __restrict__ cursor, int* __restrict__ list, int T)
{
    int t = blockIdx.x * 256 + threadIdx.x;
    if (t >= T) return;
    int e = eidx[t];
    int pos = offs[e] + atomicAdd(&cursor[e], 1);
    list[pos] = t;
}

// ---------------- prep: X -> bf16, XS (slot-ordered, scaled) -> bf16 ----------------

__global__ __launch_bounds__(256) void prep_x(
    const float* __restrict__ x, const int* __restrict__ list,
    const float* __restrict__ score, const int* __restrict__ counts,
    const int* __restrict__ offs,
    unsigned short* __restrict__ Xbf, unsigned short* __restrict__ XSbf,
    int T, int H, int E)
{
    int bid = blockIdx.x, tid = threadIdx.x;   // one block = one row; H/8 == 256
    if (bid < T) {
        const float* src = x + (size_t)bid * H + tid * 8;
        float4 a = *(const float4*)src, b = *(const float4*)(src + 4);
        *(bf16x8*)(Xbf + (size_t)bid * H + tid * 8) = pk8(a, b);
    } else {
        int s = bid - T;
        int tok = -1; float sc = 0.f;
        for (int e = 0; e < E; e++) {
            int pad = ((counts[e] + BM - 1) / BM) * BM;
            if (s >= offs[e] && s < offs[e] + pad) {
                if (s - offs[e] < counts[e]) { tok = list[s]; sc = score[tok]; }
                break;
            }
        }
        bf16x8 o;
        if (tok >= 0) {
            const float* src = x + (size_t)tok * H + tid * 8;
            float4 a = *(const float4*)src, b = *(const float4*)(src + 4);
            a.x *= sc; a.y *= sc; a.z *= sc; a.w *= sc;
            b.x *= sc; b.y *= sc; b.z *= sc; b.w *= sc;
            o = pk8(a, b);
        } else {
            o = (bf16x8){0,0,0,0,0,0,0,0};
        }
        *(bf16x8*)(XSbf + (size_t)s * H + tid * 8) = o;
    }
}

// ---------------- prep: W fp32 [B][K][N] -> bf16 [B][N][K] ----------------

__global__ __launch_bounds__(256) void transpose_cvt(
    const float* __restrict__ src, unsigned short* __restrict__ dst, int K, int N)
{
    __shared__ float t[64][65];
    src += (size_t)blockIdx.z * K * N;
    dst += (size_t)blockIdx.z * K * N;
    const int k0 = blockIdx.x * 64, n0 = blockIdx.y * 64;
    const int tid = threadIdx.x;
    const int r = tid >> 4, c = (tid & 15) * 4;
#pragma unroll
    for (int i = 0; i < 4; i++) {
        float4 v = *(const float4*)(src + (size_t)(k0 + r + 16 * i) * N + n0 + c);
        t[r + 16 * i][c + 0] = v.x; t[r + 16 * i][c + 1] = v.y;
        t[r + 16 * i][c + 2] = v.z; t[r + 16 * i][c + 3] = v.w;
    }
    __syncthreads();
    const int nl = tid >> 2, kq = (tid & 3) * 16;
    union { bf16x8 v[2]; unsigned short u[16]; } o;
#pragma unroll
    for (int j = 0; j < 16; j++) o.u[j] = f2bf(t[kq + j][nl]);
    unsigned short* d = dst + (size_t)(n0 + nl) * K + k0 + kq;
    *(bf16x8*)d = o.v[0];
    *(bf16x8*)(d + 8) = o.v[1];
}

// ---------------- up: merged shared+routed, gload_lds staging ----------------

__global__ __launch_bounds__(256) void up_gemm(
    const unsigned short* __restrict__ Xbf, const unsigned short* __restrict__ XSbf,
    const unsigned short* __restrict__ sgT, const unsigned short* __restrict__ suT,
    const unsigned short* __restrict__ gupT,
    const int* __restrict__ tile_e, const int* __restrict__ tile_m,
    const int* __restrict__ ntile, const int* __restrict__ offs,
    unsigned short* __restrict__ sharedH, unsigned short* __restrict__ routedH,
    int I, int T)
{
    const int K = 2048;
    // flatten + bijective XCD-chunk swizzle; x (tiles) fastest => same-B blocks contiguous
    const int nwg = gridDim.x * gridDim.y;
    const int hw = blockIdx.y * gridDim.x + blockIdx.x;
    const int q8 = nwg >> 3;                         // nwg % 8 == 0 by construction
    const int vid = (hw & 7) * q8 + (hw >> 3);
    const int gt = vid % gridDim.x;
    const int nb = vid / gridDim.x;
    const int TS = T / BM;

    const unsigned short *Ab, *Bg, *Bu;
    unsigned short* outP;
    int rowbase;
    if (gt < TS) {
        Ab = Xbf + (size_t)(gt * BM) * K;
        Bg = sgT + (size_t)(nb * BN) * K;
        Bu = suT + (size_t)(nb * BN) * K;
        rowbase = gt * BM; outP = sharedH;
    } else {
        int idx = gt - TS;
        if (idx >= ntile[0]) return;
        int e = tile_e[idx], mb = tile_m[idx], oe = offs[e];
        Ab = XSbf + (size_t)(oe + mb) * K;
        const unsigned short* W = gupT + (size_t)e * (2 * (size_t)I) * K;
        Bg = W + (size_t)(nb * BN) * K;
        Bu = W + (size_t)(I + nb * BN) * K;
        rowbase = oe + mb; outP = routedH;
    }

    __shared__ __attribute__((aligned(128))) short As[BM * BK];   // [128][32]
    __shared__ __attribute__((aligned(128))) short Gs[BN * BK];   // [64][32]
    __shared__ __attribute__((aligned(128))) short Us[BN * BK];

    const int tid = threadIdx.x;
    const int lane = tid & 63, wid = tid >> 6;
    const int wr = wid >> 1, wc = wid & 1;
    const int l2 = lane >> 2, la3 = lane & 3, l15 = lane & 15;
    const int kh = (lane >> 4) * 8;

    // staging sources (per-lane) and dests (wave-uniform)
    const unsigned short* sA0 = Ab + (size_t)(16 * wid + l2) * K + la3 * 8;
    const unsigned short* sA1 = Ab + (size_t)(64 + 16 * wid + l2) * K + la3 * 8;
    const unsigned short* sG  = Bg + (size_t)(16 * wid + l2) * K + la3 * 8;
    const unsigned short* sU  = Bu + (size_t)(16 * wid + l2) * K + la3 * 8;
    short* dA0 = As + wid * 512;
    short* dA1 = As + 2048 + wid * 512;
    short* dG  = Gs + wid * 512;
    short* dU  = Us + wid * 512;

    f32x4 accg[4][2], accu[4][2];
#pragma unroll
    for (int i = 0; i < 4; i++)
#pragma unroll
        for (int j = 0; j < 2; j++) {
            accg[i][j] = (f32x4){0.f, 0.f, 0.f, 0.f};
            accu[i][j] = (f32x4){0.f, 0.f, 0.f, 0.f};
        }

    const int nK = K / BK;   // 64
    for (int kt = 0; kt < nK; kt++) {
        const int k0 = kt * BK;
        gload16(sA0 + k0, dA0);
        gload16(sA1 + k0, dA1);
        gload16(sG + k0, dG);
        gload16(sU + k0, dU);
        __syncthreads();                     // vmcnt drain -> LDS tile ready
        bf16x8 af[4], gfr[2], ufr[2];
#pragma unroll
        for (int q = 0; q < 4; q++)
            af[q] = *(const bf16x8*)(As + (wr * 64 + q * 16 + l15) * BK + kh);
#pragma unroll
        for (int nj = 0; nj < 2; nj++) {
            gfr[nj] = *(const bf16x8*)(Gs + (wc * 32 + nj * 16 + l15) * BK + kh);
            ufr[nj] = *(const bf16x8*)(Us + (wc * 32 + nj * 16 + l15) * BK + kh);
        }
#pragma unroll
        for (int mi = 0; mi < 4; mi++)
#pragma unroll
            for (int nj = 0; nj < 2; nj++) {
                accg[mi][nj] = __builtin_amdgcn_mfma_f32_16x16x32_bf16(af[mi], gfr[nj], accg[mi][nj], 0, 0, 0);
                accu[mi][nj] = __builtin_amdgcn_mfma_f32_16x16x32_bf16(af[mi], ufr[nj], accu[mi][nj], 0, 0, 0);
            }
        __syncthreads();                     // frag reads done before next DMA overwrite
    }

    const int rb = (lane >> 4) * 4, cb = l15;
#pragma unroll
    for (int mi = 0; mi < 4; mi++)
#pragma unroll
        for (int nj = 0; nj < 2; nj++) {
            int col = nb * BN + wc * 32 + nj * 16 + cb;
#pragma unroll
            for (int j = 0; j < 4; j++) {
                float g = accg[mi][nj][j], u = accu[mi][nj][j];
                float r = u * g * __builtin_amdgcn_rcpf(1.f + __expf(-g));
                int row = rowbase + wr * 64 + mi * 16 + rb + j;
                outP[(size_t)row * I + col] = f2bf(r);
            }
        }
}

// ---------------- fused down: out[tok] = SH[tok]@WsdT^T + RH[slot]@dpT_e^T ----------------

__global__ __launch_bounds__(256) void fused_down(
    const unsigned short* __restrict__ SH, const unsigned short* __restrict__ RH,
    const unsigned short* __restrict__ WsdT, const unsigned short* __restrict__ dpT,
    const int* __restrict__ counts, const int* __restrict__ offs,
    const int* __restrict__ list,
    const int* __restrict__ tile_e, const int* __restrict__ tile_m,
    const int* __restrict__ ntile,
    float* __restrict__ out, int I, int H)
{
    const int nwg = gridDim.x * gridDim.y;
    const int hw = blockIdx.y * gridDim.x + blockIdx.x;
    const int q8 = nwg >> 3;
    const int vid = (hw & 7) * q8 + (hw >> 3);
    const int gt = vid % gridDim.x;
    const int nb = vid / gridDim.x;
    if (gt >= ntile[0]) return;
    const int e = tile_e[gt], mbase = tile_m[gt];
    const int count = counts[e], off_e = offs[e];

    __shared__ __attribute__((aligned(128))) short A1s[BM * BK];
    __shared__ __attribute__((aligned(128))) short A2s[BM * BK];
    __shared__ __attribute__((aligned(128))) short B1s[BN * BK];
    __shared__ __attribute__((aligned(128))) short B2s[BN * BK];
    __shared__ int toks[BM];

    const int tid = threadIdx.x;
    const int lane = tid & 63, wid = tid >> 6;
    const int wr = wid >> 1, wc = wid & 1;
    const int l2 = lane >> 2, la3 = lane & 3, l15 = lane & 15;
    const int kh = (lane >> 4) * 8;

    if (tid < BM) {
        int gr = mbase + tid;
        toks[tid] = (gr < count) ? list[off_e + gr] : -1;
    }
    __syncthreads();

    // per-thread staged rows (2 per tile-half) and their tokens
    const int R0 = 16 * wid + l2, R1 = 64 + 16 * wid + l2;
    int t0 = toks[R0]; if (t0 < 0) t0 = 0;
    int t1 = toks[R1]; if (t1 < 0) t1 = 0;
    const unsigned short* sA1_0 = SH + (size_t)t0 * I + la3 * 8;
    const unsigned short* sA1_1 = SH + (size_t)t1 * I + la3 * 8;
    const unsigned short* sA2_0 = RH + (size_t)(off_e + mbase + R0) * I + la3 * 8;
    const unsigned short* sA2_1 = RH + (size_t)(off_e + mbase + R1) * I + la3 * 8;
    const unsigned short* sB1 = WsdT + (size_t)(nb * BN + 16 * wid + l2) * I + la3 * 8;
    const unsigned short* sB2 = dpT + (size_t)e * H * I
                              + (size_t)(nb * BN + 16 * wid + l2) * I + la3 * 8;
    short* dA1_0 = A1s + wid * 512;
    short* dA1_1 = A1s + 2048 + wid * 512;
    short* dA2_0 = A2s + wid * 512;
    short* dA2_1 = A2s + 2048 + wid * 512;
    short* dB1 = B1s + wid * 512;
    short* dB2 = B2s + wid * 512;

    f32x4 acc[4][2];
#pragma unroll
    for (int i = 0; i < 4; i++)
#pragma unroll
        for (int j = 0; j < 2; j++) acc[i][j] = (f32x4){0.f, 0.f, 0.f, 0.f};

    const int nK = I / BK;   // 128
    for (int kt = 0; kt < nK; kt++) {
        const int k0 = kt * BK;
        gload16(sA1_0 + k0, dA1_0);
        gload16(sA1_1 + k0, dA1_1);
        gload16(sA2_0 + k0, dA2_0);
        gload16(sA2_1 + k0, dA2_1);
        gload16(sB1 + k0, dB1);
        gload16(sB2 + k0, dB2);
        __syncthreads();
        bf16x8 af1[4], af2[4], b1[2], b2[2];
#pragma unroll
        for (int q = 0; q < 4; q++) {
            int ro = (wr * 64 + q * 16 + l15) * BK + kh;
            af1[q] = *(const bf16x8*)(A1s + ro);
            af2[q] = *(const bf16x8*)(A2s + ro);
        }
#pragma unroll
        for (int nj = 0; nj < 2; nj++) {
            int ro = (wc * 32 + nj * 16 + l15) * BK + kh;
            b1[nj] = *(const bf16x8*)(B1s + ro);
            b2[nj] = *(const bf16x8*)(B2s + ro);
        }
#pragma unroll
        for (int mi = 0; mi < 4; mi++)
#pragma unroll
            for (int nj = 0; nj < 2; nj++) {
                acc[mi][nj] = __builtin_amdgcn_mfma_f32_16x16x32_bf16(af1[mi], b1[nj], acc[mi][nj], 0, 0, 0);
                acc[mi][nj] = __builtin_amdgcn_mfma_f32_16x16x32_bf16(af2[mi], b2[nj], acc[mi][nj], 0, 0, 0);
            }
        __syncthreads();
    }

    const int rb = (lane >> 4) * 4, cb = l15;
#pragma unroll
    for (int mi = 0; mi < 4; mi++)
#pragma unroll
        for (int nj = 0; nj < 2; nj++) {
            int col = nb * BN + wc * 32 + nj * 16 + cb;
#pragma unroll
            for (int j = 0; j < 4; j++) {
                int lr = wr * 64 + mi * 16 + rb + j;
                int tok = toks[lr];
                if (tok >= 0) out[(size_t)tok * H + col] = acc[mi][nj][j];
            }
        }
}

// ---------------- launcher ----------------

extern "C" void kernel_launch(void* const* d_in, const int* in_sizes, int n_in,
                              void* d_out, int out_size, void* d_ws, size_t ws_size,
                              hipStream_t stream)
{
    const float* x   = (const float*)d_in[0];
    const float* rw  = (const float*)d_in[1];
    const float* gup = (const float*)d_in[2];
    const float* dp  = (const float*)d_in[3];
    const float* sg  = (const float*)d_in[4];
    const float* su  = (const float*)d_in[5];
    const float* sd  = (const float*)d_in[6];

    const int H = 2048, I = 4096, E = 8;
    const int T = in_sizes[0] / H;            // 2048

    float* out        = (float*)d_out;
    float* scores_out = out + (size_t)T * H;  // router_scores [E, T]

    const int slotsCap = T + E * BM;          // 3072
    unsigned short* routedH = (unsigned short*)d_ws;                  // [slotsCap][I]
    unsigned short* sharedH = routedH + (size_t)slotsCap * I;         // [T][I]
    unsigned short* Xbf     = sharedH + (size_t)T * I;                // [T][H]
    unsigned short* XSbf    = Xbf + (size_t)T * H;                    // [slotsCap][H]
    unsigned short* gupT    = XSbf + (size_t)slotsCap * H;            // [E][2I][H]
    unsigned short* dpT     = gupT + (size_t)E * 2 * I * H;           // [E][H][I]
    unsigned short* sgT     = dpT + (size_t)E * H * I;                // [I][H]
    unsigned short* suT     = sgT + (size_t)I * H;                    // [I][H]
    unsigned short* sdT     = suT + (size_t)I * H;                    // [H][I]
    int*   list   = (int*)(sdT + (size_t)H * I);                      // [slotsCap]
    int*   eidx   = list + slotsCap;                                  // [T]
    float* score  = (float*)(eidx + T);                               // [T]
    int*   counts = (int*)(score + T);                                // [E]
    int*   cursor = counts + E;                                       // [E]
    int*   offs   = cursor + E;                                       // [E]
    int*   ntile  = offs + E;                                         // [1]
    int*   tile_e = ntile + 1;                                        // [MAXT]
    int*   tile_m = tile_e + MAXT;                                    // [MAXT]

    const int maxRTiles = T / BM + E;         // 24
    const int maxUTiles = T / BM + maxRTiles; // 40

    // weight prep (independent of routing)
    transpose_cvt<<<dim3(H / 64, I / 64, 1), 256, 0, stream>>>(sg, sgT, H, I);
    transpose_cvt<<<dim3(H / 64, I / 64, 1), 256, 0, stream>>>(su, suT, H, I);
    transpose_cvt<<<dim3(I / 64, H / 64, 1), 256, 0, stream>>>(sd, sdT, I, H);
    transpose_cvt<<<dim3(H / 64, (2 * I) / 64, E), 256, 0, stream>>>(gup, gupT, H, 2 * I);
    transpose_cvt<<<dim3(I / 64, H / 64, E), 256, 0, stream>>>(dp, dpT, I, H);

    // routing
    hipMemsetAsync(counts, 0, 2 * E * sizeof(int), stream);
    router_kernel<<<(T * E) / 256, 256, 0, stream>>>(x, rw, scores_out, eidx, score, counts, T, H, E);
    prefix_kernel<<<1, 1, 0, stream>>>(counts, offs, tile_e, tile_m, ntile, E);
    scatter_kernel<<<(T + 255) / 256, 256, 0, stream>>>(eidx, offs, cursor, list, T);
    prep_x<<<T + slotsCap, 256, 0, stream>>>(x, list, score, counts, offs, Xbf, XSbf, T, H, E);

    // GEMMs
    up_gemm<<<dim3(maxUTiles, I / BN), 256, 0, stream>>>(Xbf, XSbf, sgT, suT, gupT,
                                                         tile_e, tile_m, ntile, offs,
                                                         sharedH, routedH, I, T);
    fused_down<<<dim3(maxRTiles, H / BN), 256, 0, stream>>>(sharedH, routedH, sdT, dpT,
                                                            counts, offs, list,
                                                            tile_e, tile_m, ntile, out, I, H);
}